// Round 5
// baseline (2750.101 us; speedup 1.0000x reference)
//
#include <hip/hip_runtime.h>

// MI-LSTM on MI355X (gfx950). I/O is FP32 (per reference dtypes); compute
// uses bf16 MFMA internally (test tolerance is bf16-grade: 1.156e-2).
// B=128, T=256, D_IN=1024, UNITS=1024, N_CLASS=1024.
//
// R10: two-group latency hiding. R9's step (7.2us) was ~85% serial latency
// (h broadcast via MALL + 64-block barrier round) with the CU idle. Now each
// 512-thread block serves TWO independent 16-row groups that share one WrS
// slice (128KB, XOR-swizzled, no pad): half = 4 waves, own step loop, own
// 64-block group barrier (8 groups of 16 batch rows). No __syncthreads after
// the prologue -- halves sync via LDS-atomic wave barriers, so one half's
// barrier/MALL latency overlaps the other half's compute on the same SIMDs.
// XP is stored block-contiguous permuted ([row'][u_idx*64+j*4+g]): one u64
// per thread per step, full 64B-line utilization (kills 32MB/chunk overfetch).
// h exchange keeps R9's proven sc1 write-through + relaxed far-atomic
// barrier with executed-barrier counting (nbase).

typedef unsigned short u16;
typedef unsigned long long u64t;
typedef __attribute__((ext_vector_type(8))) short short8;   // 8 x bf16 (4 VGPRs)
typedef __attribute__((ext_vector_type(4))) float f32x4;    // MFMA accumulator

#define B_SZ   128
#define T_SZ   256
#define D_IN   1024
#define UNITS  1024
#define FOURU  4096

__device__ __forceinline__ float bf2f(u16 h) {
    return __uint_as_float(((unsigned int)h) << 16);
}
__device__ __forceinline__ u16 f2bf(float f) {
    unsigned int u = __float_as_uint(f);
    u += 0x7fffu + ((u >> 16) & 1u);   // round-to-nearest-even
    return (u16)(u >> 16);
}
__device__ __forceinline__ float sigmoidf_(float x) {
    return 1.0f / (1.0f + __expf(-x));
}

// ---------------------------------------------------------------- transpose+cvt
__global__ __launch_bounds__(256) void transpose_cvt(
    const float* __restrict__ in, u16* __restrict__ out, int K, int N)
{
    __shared__ u16 t[32][33];
    int n0 = blockIdx.x * 32, k0 = blockIdx.y * 32;
    int c = threadIdx.x & 31, r = threadIdx.x >> 5;
    #pragma unroll
    for (int i = 0; i < 4; ++i) {
        int kk = r + i * 8;
        t[kk][c] = f2bf(in[(size_t)(k0 + kk) * N + n0 + c]);
    }
    __syncthreads();
    #pragma unroll
    for (int i = 0; i < 4; ++i) {
        int nn = r + i * 8;
        out[(size_t)(n0 + nn) * K + k0 + c] = t[c][nn];
    }
}

// ---------------------------------------------------------------- XP GEMM (one time-chunk)
// Permuted output: Cc[rowp][ (u/16)*64 + (u%16)*4 + gate ], rowp = b*tc + tt.
__global__ __launch_bounds__(256) void gemm_xp_chunk(
    const float* __restrict__ X, const u16* __restrict__ Bt,
    const float* __restrict__ bias, u16* __restrict__ Cc,
    int t0, int tcShift)
{
    __shared__ __align__(16) u16 As[128 * 40];
    __shared__ __align__(16) u16 Bs[128 * 40];
    int tid = threadIdx.x;
    int wave = tid >> 6, lane = tid & 63;
    int bm = blockIdx.x * 128;     // row' base, row' = b*tc + tt
    int bn = blockIdx.y * 128;
    int wm = (wave & 1) * 64, wn = (wave >> 1) * 64;
    int lm = lane & 15, lq = lane >> 4;
    int tcMask = (1 << tcShift) - 1;

    f32x4 acc[4][4] = {};

    for (int k0 = 0; k0 < D_IN; k0 += 32) {
        #pragma unroll
        for (int i = 0; i < 2; ++i) {
            int idx = tid + i * 256;
            int r = idx >> 2, q = idx & 3;
            int rowp = bm + r;
            int b = rowp >> tcShift;
            int tt = rowp & tcMask;
            const float* xs = &X[(size_t)(b * T_SZ + t0 + tt) * D_IN + k0 + q * 8];
            float4 f0 = *(const float4*)xs;
            float4 f1 = *(const float4*)(xs + 4);
            uint4 v;
            v.x = (unsigned)f2bf(f0.x) | ((unsigned)f2bf(f0.y) << 16);
            v.y = (unsigned)f2bf(f0.z) | ((unsigned)f2bf(f0.w) << 16);
            v.z = (unsigned)f2bf(f1.x) | ((unsigned)f2bf(f1.y) << 16);
            v.w = (unsigned)f2bf(f1.z) | ((unsigned)f2bf(f1.w) << 16);
            *(uint4*)&As[r * 40 + q * 8] = v;
            *(uint4*)&Bs[r * 40 + q * 8] =
                *(const uint4*)&Bt[(size_t)(bn + r) * D_IN + k0 + q * 8];
        }
        __syncthreads();
        short8 af[4], bf[4];
        #pragma unroll
        for (int t = 0; t < 4; ++t) {
            af[t] = *(const short8*)&As[(wm + t * 16 + lm) * 40 + lq * 8];
            bf[t] = *(const short8*)&Bs[(wn + t * 16 + lm) * 40 + lq * 8];
        }
        #pragma unroll
        for (int mt = 0; mt < 4; ++mt)
            #pragma unroll
            for (int nt = 0; nt < 4; ++nt)
                acc[mt][nt] = __builtin_amdgcn_mfma_f32_16x16x32_bf16(
                    af[mt], bf[nt], acc[mt][nt], 0, 0, 0);
        __syncthreads();
    }

    #pragma unroll
    for (int mt = 0; mt < 4; ++mt) {
        #pragma unroll
        for (int nt = 0; nt < 4; ++nt) {
            int col = bn + wn + nt * 16 + lm;        // n in [0,4096)
            int g = col >> 10, w = col & 1023;
            int colp = ((w >> 4) << 6) + ((w & 15) << 2) + g;  // permuted
            float bv = bias[col];
            #pragma unroll
            for (int r = 0; r < 4; ++r) {
                int rowp = bm + wm + mt * 16 + lq * 4 + r;
                Cc[(size_t)rowp * FOURU + colp] = f2bf(acc[mt][nt][r] + bv);
            }
        }
    }
}

// ---------------------------------------------------------------- persistent LSTM chunk (R10)
// 256 blocks x 512 threads (8 waves). bid -> u_idx = bid&63 (16 u-cols,
// 64 n-cols), gpair = bid>>6. Half h (=tid>>8) serves group 2*gpair+h:
// batch rows [gpair*32 + h*16, +16). WrS (64 n-rows x 1024 k, 128KB,
// st-16B XOR swizzle) shared by both halves, staged once per chunk.
// Per half-step: 4 waves split K in quarters; A = 16 rows x 256 k sc1 u64
// loads; 32 MFMA; zbuf 2-layer write+RMW reduce; fused MI epilogue (1 cell
// per thread); sc1 h store; LDS-sync; leader runs 64-block group barrier.
__global__ __launch_bounds__(512) void milstm_chunk(
    const u16* __restrict__ XPc,     // permuted bf16 [128*tc][4096]
    const u16* __restrict__ WrT,     // [4096][1024] bf16
    const float* __restrict__ br,
    const float* __restrict__ alpha,
    const float* __restrict__ beta1,
    const float* __restrict__ beta2,
    const u16* __restrict__ h0bf,    // [128][1024] bf16
    u16* __restrict__ hb0,
    u16* __restrict__ hb1,
    float* __restrict__ cbuf,        // [128][1024] f32
    unsigned* __restrict__ bar,      // 8 groups x 256 u32 (zeroed at t=0)
    int t0, int tc, int nbase)
{
    __shared__ __align__(16) u16 WrS[64 * 1024];     // 128 KB, XOR-swizzled
    __shared__ float zbuf[2][2][64][17];             // [half][L][n-loc][m] 17 KB
    __shared__ float brS[64], alS[64], b1S[64], b2S[64];
    __shared__ unsigned hsync[2];                    // per-half arrive counter
    __shared__ unsigned hflag[2];                    // per-half release flag

    int tid = threadIdx.x;
    int bid = blockIdx.x;
    int u_idx = bid & 63, gpair = bid >> 6;
    int u0 = u_idx * 16;
    int half = tid >> 8;
    int x = tid & 255;
    int kq = x >> 6;                  // wave-in-half: K quarter
    int lane = tid & 63;
    int lm = lane & 15, lq = lane >> 4;
    int grpRow0 = gpair * 32 + half * 16;
    int group = gpair * 2 + half;     // 0..7
    unsigned gBase = (unsigned)group * 256u;
    unsigned sub = (unsigned)(u_idx >> 4);   // 4 subs x 16 blocks

    // ---- prologue (whole block; the ONLY __syncthreads region) ----
    // stage WrS: 64 rows x 1024 bf16, swizzled: byte = l*2048 + (q*16 ^ ((l&7)<<4))
    #pragma unroll
    for (int it = 0; it < 16; ++it) {
        int idx = it * 512 + tid;
        int l = idx >> 7, q = idx & 127;
        int n = ((l >> 4) << 10) + u0 + (l & 15);
        int byte = l * 2048 + ((q * 16) ^ ((l & 7) << 4));
        *(uint4*)((char*)WrS + byte) = *(const uint4*)&WrT[(size_t)n * 1024 + q * 8];
    }
    if (tid < 64) {
        int n = ((tid >> 4) << 10) + u0 + (tid & 15);
        brS[tid] = br[n]; alS[tid] = alpha[n];
        b1S[tid] = beta1[n]; b2S[tid] = beta2[n];
    }
    if (tid < 2) { hsync[tid] = 0u; hflag[tid] = 0u; }

    // epilogue cell ownership: j = x&15 (u-col), m = x>>4 (row-in-16)
    int ej = x & 15, em = x >> 4;
    int erow = grpRow0 + em;
    size_t hixE = (size_t)erow * UNITS + u0 + ej;    // h/c cell index
    float cv = cbuf[hixE];
    // XP prefetch s=0: 4 gates for (erow, ej) = one u64 (permuted layout)
    u64t xq = *(const u64t*)&XPc[(size_t)(erow * tc) * FOURU + (u_idx << 6) + (ej << 2)];
    __syncthreads();
    // ---- no __syncthreads beyond this point ----

    unsigned st = 0;                  // LDS sync target accumulator (per half)
    volatile unsigned* cnt = &hsync[half];

    for (int s = 0; s < tc; ++s) {
        int t = t0 + s;
        const u16* hsrc = (t == 0) ? h0bf : ((t & 1) ? hb0 : hb1);
        u16* hdst = (t & 1) ? hb1 : hb0;

        // ---- A burst: 16 rows x 256 k (this wave's K-quarter), sc1 u64 x16
        const u64t* A0 = (const u64t*)
            &hsrc[(size_t)(grpRow0 + lm) * UNITS + kq * 256 + lq * 8];
        u64t aq[16];
        #pragma unroll
        for (int i = 0; i < 8; ++i) {
            aq[2 * i]     = __hip_atomic_load(A0 + i * 8,     __ATOMIC_RELAXED, __HIP_MEMORY_SCOPE_AGENT);
            aq[2 * i + 1] = __hip_atomic_load(A0 + i * 8 + 1, __ATOMIC_RELAXED, __HIP_MEMORY_SCOPE_AGENT);
        }

        // ---- MFMA: 8 k-iters x 4 gates; B from swizzled WrS
        f32x4 acc0 = {}, acc1 = {}, acc2 = {}, acc3 = {};
        const char* Wb = (const char*)WrS;
        int swz = (lm & 7) << 4;
        #pragma unroll
        for (int i = 0; i < 8; ++i) {
            union { u64t q[2]; short8 v; } a;
            a.q[0] = aq[2 * i]; a.q[1] = aq[2 * i + 1];
            int cb = ((kq * 512 + i * 64 + lq * 16) ^ swz);
            short8 b0 = *(const short8*)(Wb + (0 * 16 + lm) * 2048 + cb);
            short8 b1 = *(const short8*)(Wb + (1 * 16 + lm) * 2048 + cb);
            short8 b2 = *(const short8*)(Wb + (2 * 16 + lm) * 2048 + cb);
            short8 b3 = *(const short8*)(Wb + (3 * 16 + lm) * 2048 + cb);
            acc0 = __builtin_amdgcn_mfma_f32_16x16x32_bf16(a.v, b0, acc0, 0, 0, 0);
            acc1 = __builtin_amdgcn_mfma_f32_16x16x32_bf16(a.v, b1, acc1, 0, 0, 0);
            acc2 = __builtin_amdgcn_mfma_f32_16x16x32_bf16(a.v, b2, acc2, 0, 0, 0);
            acc3 = __builtin_amdgcn_mfma_f32_16x16x32_bf16(a.v, b3, acc3, 0, 0, 0);
        }

        // ---- zbuf reduce: waves 0,1 write layers 0,1; waves 2,3 add into them
        if (kq < 2) {
            #pragma unroll
            for (int r = 0; r < 4; ++r) {
                int m = lq * 4 + r;
                zbuf[half][kq][0 * 16 + lm][m] = acc0[r];
                zbuf[half][kq][1 * 16 + lm][m] = acc1[r];
                zbuf[half][kq][2 * 16 + lm][m] = acc2[r];
                zbuf[half][kq][3 * 16 + lm][m] = acc3[r];
            }
        }
        // sync_b: writers done
        {
            st += 4;
            asm volatile("s_waitcnt lgkmcnt(0)" ::: "memory");
            if (lane == 0)
                __hip_atomic_fetch_add((unsigned*)cnt, 1u, __ATOMIC_RELAXED, __HIP_MEMORY_SCOPE_WORKGROUP);
            while (__hip_atomic_load((unsigned*)cnt, __ATOMIC_RELAXED, __HIP_MEMORY_SCOPE_WORKGROUP) < st)
                __builtin_amdgcn_s_sleep(1);
        }
        if (kq >= 2) {
            int L = kq - 2;
            #pragma unroll
            for (int r = 0; r < 4; ++r) {
                int m = lq * 4 + r;
                zbuf[half][L][0 * 16 + lm][m] += acc0[r];
                zbuf[half][L][1 * 16 + lm][m] += acc1[r];
                zbuf[half][L][2 * 16 + lm][m] += acc2[r];
                zbuf[half][L][3 * 16 + lm][m] += acc3[r];
            }
        }
        // sync_c: adders done
        {
            st += 4;
            asm volatile("s_waitcnt lgkmcnt(0)" ::: "memory");
            if (lane == 0)
                __hip_atomic_fetch_add((unsigned*)cnt, 1u, __ATOMIC_RELAXED, __HIP_MEMORY_SCOPE_WORKGROUP);
            while (__hip_atomic_load((unsigned*)cnt, __ATOMIC_RELAXED, __HIP_MEMORY_SCOPE_WORKGROUP) < st)
                __builtin_amdgcn_s_sleep(1);
        }

        // ---- fused MI epilogue: one cell (erow, u0+ej) per thread
        {
            float zz[4];
            #pragma unroll
            for (int g = 0; g < 4; ++g) {
                int l = g * 16 + ej;
                float hp = zbuf[half][0][l][em] + zbuf[half][1][l][em] + brS[l];
                float xp = bf2f((u16)(xq >> (16 * g)));
                zz[g] = alS[l] * xp * hp + b1S[l] * xp + b2S[l] * hp;
            }
            float cn = tanhf(zz[2]) * sigmoidf_(zz[0]) + cv * sigmoidf_(zz[1]);
            cv = cn;
            u16 hv = f2bf(tanhf(cn) * sigmoidf_(zz[3]));
            __hip_atomic_store(&hdst[hixE], hv, __ATOMIC_RELAXED, __HIP_MEMORY_SCOPE_AGENT);
        }

        if (s + 1 < tc) {
            // drain h stores, then issue next-step XP prefetch (stays in
            // flight across the barrier; consumed next iteration)
            asm volatile("s_waitcnt vmcnt(0)" ::: "memory");
            xq = *(const u64t*)&XPc[(size_t)(erow * tc + s + 1) * FOURU
                                    + (u_idx << 6) + (ej << 2)];

            // sync_d: all 4 waves arrived with h stored
            st += 4;
            asm volatile("s_waitcnt lgkmcnt(0)" ::: "memory");
            if (lane == 0)
                __hip_atomic_fetch_add((unsigned*)cnt, 1u, __ATOMIC_RELAXED, __HIP_MEMORY_SCOPE_WORKGROUP);
            while (__hip_atomic_load((unsigned*)cnt, __ATOMIC_RELAXED, __HIP_MEMORY_SCOPE_WORKGROUP) < st)
                __builtin_amdgcn_s_sleep(1);

            // group barrier (64 half-blocks): leader only
            if (x == 0) {
                unsigned barId = (unsigned)(nbase + s + 1);
                unsigned old = __hip_atomic_fetch_add(&bar[gBase + sub * 32u], 1u,
                                   __ATOMIC_RELAXED, __HIP_MEMORY_SCOPE_AGENT);
                if (old == 16u * barId - 1u)
                    __hip_atomic_fetch_add(&bar[gBase + 128u], 1u,
                        __ATOMIC_RELAXED, __HIP_MEMORY_SCOPE_AGENT);
                while (__hip_atomic_load(&bar[gBase + 128u],
                           __ATOMIC_RELAXED, __HIP_MEMORY_SCOPE_AGENT)
                       < 4u * barId)
                    __builtin_amdgcn_s_sleep(2);
                __hip_atomic_store(&hflag[half], (unsigned)(s + 1),
                                   __ATOMIC_RELAXED, __HIP_MEMORY_SCOPE_WORKGROUP);
            }
            // sync_e: all lanes wait for leader's release
            while (__hip_atomic_load(&hflag[half], __ATOMIC_RELAXED, __HIP_MEMORY_SCOPE_WORKGROUP)
                   < (unsigned)(s + 1))
                __builtin_amdgcn_s_sleep(1);
        }
    }

    // c-state writeback once per chunk
    cbuf[hixE] = cv;
}

// ---------------------------------------------------------------- final GEMM
__global__ __launch_bounds__(256) void gemm_out(
    const u16* __restrict__ h, const u16* __restrict__ WcT,
    const float* __restrict__ bc, float* __restrict__ out)
{
    int tid = threadIdx.x;
    int wave = tid >> 6, lane = tid & 63;
    int bx = blockIdx.x;
    int row0 = (bx & 7) * 16;
    int n0 = (bx >> 3) * 64 + wave * 16;
    int lm = lane & 15, lq = lane >> 4;

    f32x4 acc = {};
    const u16* Arow = &h[(size_t)(row0 + lm) * UNITS];
    const u16* Brow = &WcT[(size_t)(n0 + lm) * UNITS];
    #pragma unroll 8
    for (int k0 = 0; k0 < UNITS; k0 += 32) {
        short8 a = *(const short8*)&Arow[k0 + lq * 8];
        short8 b = *(const short8*)&Brow[k0 + lq * 8];
        acc = __builtin_amdgcn_mfma_f32_16x16x32_bf16(a, b, acc, 0, 0, 0);
    }
    int col = n0 + lm;
    float bv = bc[col];
    #pragma unroll
    for (int r = 0; r < 4; ++r) {
        int row = row0 + lq * 4 + r;
        out[(size_t)row * 1024 + col] = acc[r] + bv;
    }
}

// ---------------------------------------------------------------- utilities
__global__ void cvt_f32_bf16(const float* __restrict__ in, u16* __restrict__ out, int n) {
    int i = blockIdx.x * 256 + threadIdx.x;
    if (i < n) out[i] = f2bf(in[i]);
}
__global__ void cvt_bf16_f32(const u16* __restrict__ in, float* __restrict__ out, int n) {
    int i = blockIdx.x * 256 + threadIdx.x;
    if (i < n) out[i] = bf2f(in[i]);
}
__global__ void copy_f32(const float* __restrict__ in, float* __restrict__ out, int n) {
    int i = blockIdx.x * 256 + threadIdx.x;
    if (i < n) out[i] = in[i];
}
__global__ void zero_u32(unsigned* __restrict__ p, int n) {
    int i = blockIdx.x * 256 + threadIdx.x;
    if (i < n) p[i] = 0u;
}

// ---------------------------------------------------------------- launch
extern "C" void kernel_launch(void* const* d_in, const int* in_sizes, int n_in,
                              void* d_out, int out_size, void* d_ws, size_t ws_size,
                              hipStream_t stream)
{
    const float* x     = (const float*)d_in[0];   // [128,256,1024]
    const float* h0    = (const float*)d_in[1];   // [128,1024]
    const float* c0    = (const float*)d_in[2];   // [128,1024]
    const float* Wk    = (const float*)d_in[3];   // [1024,4096]
    const float* bk    = (const float*)d_in[4];   // [4096]
    const float* Wr    = (const float*)d_in[5];   // [1024,4096]
    const float* br    = (const float*)d_in[6];   // [4096]
    const float* alpha = (const float*)d_in[7];   // [1,4096]
    const float* beta1 = (const float*)d_in[8];   // [1,4096]
    const float* beta2 = (const float*)d_in[9];   // [1,4096]
    const float* Wc    = (const float*)d_in[10];  // [1024,1024]
    const float* bc    = (const float*)d_in[11];  // [1024]
    float* out = (float*)d_out;                   // out|h|c, each 128*1024 fp32

    char* p = (char*)d_ws;
    u16* h0bf = (u16*)p;  p += (size_t)B_SZ * UNITS * 2;
    u16* hb0  = (u16*)p;  p += (size_t)B_SZ * UNITS * 2;
    u16* hb1  = (u16*)p;  p += (size_t)B_SZ * UNITS * 2;
    float* cbuf = (float*)p; p += (size_t)B_SZ * UNITS * 4;
    unsigned* bar = (unsigned*)p; p += 8 * 256 * 4;   // 8 groups x 1KB
    u16* WkT = (u16*)p;   p += (size_t)FOURU * D_IN * 2;
    u16* WrT = (u16*)p;   p += (size_t)FOURU * UNITS * 2;
    u16* WcT = (u16*)p;   p += (size_t)1024 * 1024 * 2;
    u16* XPc = (u16*)p;   // bf16 permuted [B_SZ*tc][4096]

    size_t fixedB = (size_t)(p - (char*)d_ws);
    int tc = 32, tcShift = 5;
    while (tc > 1 && fixedB + (size_t)B_SZ * tc * FOURU * 2 > ws_size) {
        tc >>= 1; tcShift -= 1;
    }

    // 1) weight transposes + fp32->bf16 convert
    transpose_cvt<<<dim3(FOURU / 32, D_IN / 32), 256, 0, stream>>>(Wk, WkT, D_IN, FOURU);
    transpose_cvt<<<dim3(FOURU / 32, UNITS / 32), 256, 0, stream>>>(Wr, WrT, UNITS, FOURU);
    transpose_cvt<<<dim3(1024 / 32, 1024 / 32), 256, 0, stream>>>(Wc, WcT, 1024, 1024);

    // 2) state init
    cvt_f32_bf16<<<(B_SZ * UNITS) / 256, 256, 0, stream>>>(h0, h0bf, B_SZ * UNITS);
    copy_f32<<<(B_SZ * UNITS) / 256, 256, 0, stream>>>(c0, cbuf, B_SZ * UNITS);
    zero_u32<<<8, 256, 0, stream>>>(bar, 2048);

    // 3) recurrence: per chunk, XP GEMM then one persistent chunk kernel.
    //    256 blocks x 512 thr, ~150KB LDS -> 1 block/CU, all resident.
    for (int t0 = 0; t0 < T_SZ; t0 += tc) {
        gemm_xp_chunk<<<dim3(tc, FOURU / 128), 256, 0, stream>>>(
            x, WkT, bk, XPc, t0, tcShift);
        int nbase = (t0 / tc) * (tc - 1);   // executed barriers before chunk
        milstm_chunk<<<256, 512, 0, stream>>>(
            XPc, WrT, br, alpha, beta1, beta2, h0bf, hb0, hb1, cbuf, bar,
            t0, tc, nbase);
    }
    // T=256 even -> final h in hb1

    // 4) out = h @ Wc + bc ; emit h (bf16->f32), c (f32)
    gemm_out<<<128, 256, 0, stream>>>(hb1, WcT, bc, out);
    cvt_bf16_f32<<<(B_SZ * UNITS) / 256, 256, 0, stream>>>(hb1, out + B_SZ * UNITS, B_SZ * UNITS);
    copy_f32<<<(B_SZ * UNITS) / 256, 256, 0, stream>>>(cbuf, out + 2 * B_SZ * UNITS, B_SZ * UNITS);
}

// Round 6
// 2248.039 us; speedup vs baseline: 1.2233x; 1.2233x over previous
//
#include <hip/hip_runtime.h>

// MI-LSTM on MI355X (gfx950). I/O is FP32 (per reference dtypes); compute
// uses bf16 MFMA internally (test tolerance is bf16-grade: 1.156e-2).
// B=128, T=256, D_IN=1024, UNITS=1024, N_CLASS=1024.
//
// R11: weights half-in-registers to widen the column cover. R9/R10's step was
// pinned ~7.5us by h-broadcast BW (16MB/step: 64 blocks x group-h) + 64-block
// barrier; 64 cols/block was the LDS limit for full-K bf16 WrS. Now each
// block covers 128 n-cols (32 u x 4 gates): each of 8 waves holds its
// (k-half x 32-col) Wr slice in 128 VGPRs (loaded once per chunk), LDS keeps
// only a 32KB XOR-swizzled per-step h-stage + zbuf. Covering blocks 64->32:
// h-broadcast 16->8 MB/step, 32-block barrier. Groups: 8 x 16 rows.
// Waves: kh=wave>>2 (K-half), nq=wave&3 (col quarter); 2-layer zbuf reduce;
// fused MI epilogue 1 cell/thread; plain __syncthreads everywhere (R10's
// LDS-atomic sync machinery deleted). h exchange: R9-proven sc1 relaxed
// atomics + executed-barrier-counted far-atomic group barrier (nbase).

typedef unsigned short u16;
typedef unsigned long long u64t;
typedef __attribute__((ext_vector_type(8))) short short8;   // 8 x bf16 (4 VGPRs)
typedef __attribute__((ext_vector_type(4))) float f32x4;    // MFMA accumulator

#define B_SZ   128
#define T_SZ   256
#define D_IN   1024
#define UNITS  1024
#define FOURU  4096

__device__ __forceinline__ float bf2f(u16 h) {
    return __uint_as_float(((unsigned int)h) << 16);
}
__device__ __forceinline__ u16 f2bf(float f) {
    unsigned int u = __float_as_uint(f);
    u += 0x7fffu + ((u >> 16) & 1u);   // round-to-nearest-even
    return (u16)(u >> 16);
}
__device__ __forceinline__ float sigmoidf_(float x) {
    return 1.0f / (1.0f + __expf(-x));
}

// ---------------------------------------------------------------- transpose+cvt
__global__ __launch_bounds__(256) void transpose_cvt(
    const float* __restrict__ in, u16* __restrict__ out, int K, int N)
{
    __shared__ u16 t[32][33];
    int n0 = blockIdx.x * 32, k0 = blockIdx.y * 32;
    int c = threadIdx.x & 31, r = threadIdx.x >> 5;
    #pragma unroll
    for (int i = 0; i < 4; ++i) {
        int kk = r + i * 8;
        t[kk][c] = f2bf(in[(size_t)(k0 + kk) * N + n0 + c]);
    }
    __syncthreads();
    #pragma unroll
    for (int i = 0; i < 4; ++i) {
        int nn = r + i * 8;
        out[(size_t)(n0 + nn) * K + k0 + c] = t[c][nn];
    }
}

// ---------------------------------------------------------------- XP GEMM (one time-chunk)
// Permuted output: Cc[rowp][ (n&1023)*4 + (n>>10) ], rowp = b*tc + tt.
// (u-major, gate-minor: epilogue's 4 gates of one u = one u64.)
__global__ __launch_bounds__(256) void gemm_xp_chunk(
    const float* __restrict__ X, const u16* __restrict__ Bt,
    const float* __restrict__ bias, u16* __restrict__ Cc,
    int t0, int tcShift)
{
    __shared__ __align__(16) u16 As[128 * 40];
    __shared__ __align__(16) u16 Bs[128 * 40];
    int tid = threadIdx.x;
    int wave = tid >> 6, lane = tid & 63;
    int bm = blockIdx.x * 128;     // row' base, row' = b*tc + tt
    int bn = blockIdx.y * 128;
    int wm = (wave & 1) * 64, wn = (wave >> 1) * 64;
    int lm = lane & 15, lq = lane >> 4;
    int tcMask = (1 << tcShift) - 1;

    f32x4 acc[4][4] = {};

    for (int k0 = 0; k0 < D_IN; k0 += 32) {
        #pragma unroll
        for (int i = 0; i < 2; ++i) {
            int idx = tid + i * 256;
            int r = idx >> 2, q = idx & 3;
            int rowp = bm + r;
            int b = rowp >> tcShift;
            int tt = rowp & tcMask;
            const float* xs = &X[(size_t)(b * T_SZ + t0 + tt) * D_IN + k0 + q * 8];
            float4 f0 = *(const float4*)xs;
            float4 f1 = *(const float4*)(xs + 4);
            uint4 v;
            v.x = (unsigned)f2bf(f0.x) | ((unsigned)f2bf(f0.y) << 16);
            v.y = (unsigned)f2bf(f0.z) | ((unsigned)f2bf(f0.w) << 16);
            v.z = (unsigned)f2bf(f1.x) | ((unsigned)f2bf(f1.y) << 16);
            v.w = (unsigned)f2bf(f1.z) | ((unsigned)f2bf(f1.w) << 16);
            *(uint4*)&As[r * 40 + q * 8] = v;
            *(uint4*)&Bs[r * 40 + q * 8] =
                *(const uint4*)&Bt[(size_t)(bn + r) * D_IN + k0 + q * 8];
        }
        __syncthreads();
        short8 af[4], bf[4];
        #pragma unroll
        for (int t = 0; t < 4; ++t) {
            af[t] = *(const short8*)&As[(wm + t * 16 + lm) * 40 + lq * 8];
            bf[t] = *(const short8*)&Bs[(wn + t * 16 + lm) * 40 + lq * 8];
        }
        #pragma unroll
        for (int mt = 0; mt < 4; ++mt)
            #pragma unroll
            for (int nt = 0; nt < 4; ++nt)
                acc[mt][nt] = __builtin_amdgcn_mfma_f32_16x16x32_bf16(
                    af[mt], bf[nt], acc[mt][nt], 0, 0, 0);
        __syncthreads();
    }

    #pragma unroll
    for (int mt = 0; mt < 4; ++mt) {
        #pragma unroll
        for (int nt = 0; nt < 4; ++nt) {
            int col = bn + wn + nt * 16 + lm;            // n in [0,4096)
            int colp = ((col & 1023) << 2) | (col >> 10);
            float bv = bias[col];
            #pragma unroll
            for (int r = 0; r < 4; ++r) {
                int rowp = bm + wm + mt * 16 + lq * 4 + r;
                Cc[(size_t)rowp * FOURU + colp] = f2bf(acc[mt][nt][r] + bv);
            }
        }
    }
}

// ---------------------------------------------------------------- persistent LSTM chunk (R11)
// 256 blocks x 512 threads. grp = bid>>5 (8 groups x 16 batch rows),
// cb = bid&31 -> u in [cb*32, cb*32+32) = 128 n-cols (col c: u_loc=c>>2,
// gate=c&3). Wave w: kh=w>>2 (K-half), nq=w&3 (32-col quarter). Wr slice for
// (kh, 32 cols) lives in 32 short8 = 128 VGPR per lane, loaded once/chunk.
// Per step: 512 thr stage group-h (16 rows x 2KB, sc1 u64 loads) into
// XOR-swizzled LDS -> 16 MFMA k-iters x 2 col-tiles per wave -> zbuf[kh]
// -> fused MI epilogue (1 cell/thread) -> sc1 u16 h-store -> 32-block
// far-atomic group barrier (single counter, executed-barrier monotonic).
__global__ __launch_bounds__(512) void milstm_chunk(
    const u16* __restrict__ XPc,     // permuted bf16 [128*tc][4096]
    const u16* __restrict__ WrT,     // [4096][1024] bf16
    const float* __restrict__ br,
    const float* __restrict__ alpha,
    const float* __restrict__ beta1,
    const float* __restrict__ beta2,
    const u16* __restrict__ h0bf,    // [128][1024] bf16
    u16* __restrict__ hb0,
    u16* __restrict__ hb1,
    float* __restrict__ cbuf,        // [128][1024] f32
    unsigned* __restrict__ bar,      // 8 groups x 64 u32 lines (zeroed at t=0)
    int t0, int tc, int tcShift, int nbase)
{
    __shared__ __align__(16) u16 hS[16 * 1024];       // 32KB, XOR-swizzled
    __shared__ __align__(16) float zb[2][128][20];    // 20.5KB, padded
    __shared__ float brS[128], alS[128], b1S[128], b2S[128];

    int tid = threadIdx.x;
    int wave = tid >> 6, lane = tid & 63;
    int lm = lane & 15, lq = lane >> 4;
    int kh = wave >> 2, nq = wave & 3;
    int bid = blockIdx.x;
    int grp = bid >> 5, cb = bid & 31;
    int row0 = grp * 16;
    int ubase = cb * 32;
    unsigned gOff = (unsigned)grp * 64u;

    // ---- prologue ----
    // biases for the block's 128 cols (c = u_loc*4 + g)
    if (tid < 128) {
        int n = ((tid & 3) << 10) + ubase + (tid >> 2);
        brS[tid] = br[n]; alS[tid] = alpha[n];
        b1S[tid] = beta1[n]; b2S[tid] = beta2[n];
    }
    // Wr slice into registers: 16 k-iters x 2 col-tiles, 128 VGPR/lane
    short8 Breg[32];
    #pragma unroll
    for (int j = 0; j < 16; ++j) {
        #pragma unroll
        for (int nt = 0; nt < 2; ++nt) {
            int c = nq * 32 + nt * 16 + lm;
            int n = ((c & 3) << 10) + ubase + (c >> 2);
            int k = kh * 512 + j * 32 + lq * 8;
            Breg[j * 2 + nt] = *(const short8*)&WrT[(size_t)n * 1024 + k];
        }
    }
    // epilogue cell: row = tid&15, u_loc = tid>>4
    int erow = tid & 15, eul = tid >> 4;
    size_t hix = (size_t)(row0 + erow) * UNITS + ubase + eul;
    float cv = cbuf[hix];
    u64t xq = *(const u64t*)&XPc[((size_t)((row0 + erow) << tcShift) + 0) * FOURU
                                 + (size_t)(ubase + eul) * 4];
    // h-stage thread mapping: row sr = tid>>5, 64B chunk sc = tid&31
    int sr = tid >> 5, sc = tid & 31;
    unsigned swzS = (unsigned)((sr & 7) << 4);

    for (int s = 0; s < tc; ++s) {
        int t = t0 + s;
        const u16* hsrc = (t == 0) ? h0bf : ((t & 1) ? hb0 : hb1);
        u16* hdst = (t & 1) ? hb1 : hb0;

        // ---- stage group-h into LDS: 8 sc1 u64 loads + 4 swizzled b128 writes
        {
            const u64t* hp8 = (const u64t*)&hsrc[(size_t)(row0 + sr) * UNITS] + sc * 8;
            u64t aq[8];
            #pragma unroll
            for (int i = 0; i < 8; ++i)
                aq[i] = __hip_atomic_load(hp8 + i, __ATOMIC_RELAXED, __HIP_MEMORY_SCOPE_AGENT);
            char* dst = (char*)hS + sr * 2048;
            int base = sc * 64;
            #pragma unroll
            for (int q = 0; q < 4; ++q) {
                uint4 v;
                v.x = (unsigned)aq[2 * q];     v.y = (unsigned)(aq[2 * q] >> 32);
                v.z = (unsigned)aq[2 * q + 1]; v.w = (unsigned)(aq[2 * q + 1] >> 32);
                *(uint4*)(dst + (((unsigned)(base + q * 16)) ^ swzS)) = v;
            }
        }
        __syncthreads();   // sync1: h-stage (and prologue LDS on s=0) ready

        // ---- hp partial GEMM: 16 k-iters, A from swizzled hS, B from regs
        f32x4 acc0 = {}, acc1 = {};
        {
            unsigned swzA = (unsigned)((lm & 7) << 4);
            const char* hb = (const char*)hS + lm * 2048;
            #pragma unroll
            for (int j = 0; j < 16; ++j) {
                unsigned koff = (unsigned)(kh * 1024 + j * 64 + lq * 16);
                short8 a = *(const short8*)(hb + (koff ^ swzA));
                acc0 = __builtin_amdgcn_mfma_f32_16x16x32_bf16(a, Breg[j * 2],     acc0, 0, 0, 0);
                acc1 = __builtin_amdgcn_mfma_f32_16x16x32_bf16(a, Breg[j * 2 + 1], acc1, 0, 0, 0);
            }
        }
        *(f32x4*)&zb[kh][nq * 32 + lm][lq * 4]      = acc0;
        *(f32x4*)&zb[kh][nq * 32 + 16 + lm][lq * 4] = acc1;
        __syncthreads();   // sync2: both zbuf layers complete

        // ---- fused MI epilogue: cell (row0+erow, ubase+eul)
        {
            float zz[4];
            #pragma unroll
            for (int g = 0; g < 4; ++g) {
                int c = eul * 4 + g;
                float hp = zb[0][c][erow] + zb[1][c][erow] + brS[c];
                float xp = bf2f((u16)(xq >> (16 * g)));
                zz[g] = alS[c] * xp * hp + b1S[c] * xp + b2S[c] * hp;
            }
            float cn = tanhf(zz[2]) * sigmoidf_(zz[0]) + cv * sigmoidf_(zz[1]);
            cv = cn;
            u16 hv = f2bf(tanhf(cn) * sigmoidf_(zz[3]));
            __hip_atomic_store(&hdst[hix], hv, __ATOMIC_RELAXED, __HIP_MEMORY_SCOPE_AGENT);
        }
        if (s + 1 < tc) {
            // next-step XP prefetch (plain cached load; XPc constant in chunk)
            xq = *(const u64t*)&XPc[((size_t)((row0 + erow) << tcShift) + s + 1) * FOURU
                                     + (size_t)(ubase + eul) * 4];
            __syncthreads();   // sync3: h sc1 stores vmcnt-drained block-wide
            if (tid == 0) {
                unsigned barId = (unsigned)(nbase + s + 1);
                __hip_atomic_fetch_add(&bar[gOff], 1u,
                    __ATOMIC_RELAXED, __HIP_MEMORY_SCOPE_AGENT);
                while (__hip_atomic_load(&bar[gOff],
                           __ATOMIC_RELAXED, __HIP_MEMORY_SCOPE_AGENT)
                       < 32u * barId)
                    __builtin_amdgcn_s_sleep(1);
            }
            __syncthreads();   // sync4: release; safe to overwrite hS/zb
        }
    }

    // c-state writeback once per chunk (plain; kernel-end release flushes)
    cbuf[hix] = cv;
}

// ---------------------------------------------------------------- final GEMM
__global__ __launch_bounds__(256) void gemm_out(
    const u16* __restrict__ h, const u16* __restrict__ WcT,
    const float* __restrict__ bc, float* __restrict__ out)
{
    int tid = threadIdx.x;
    int wave = tid >> 6, lane = tid & 63;
    int bx = blockIdx.x;
    int row0 = (bx & 7) * 16;
    int n0 = (bx >> 3) * 64 + wave * 16;
    int lm = lane & 15, lq = lane >> 4;

    f32x4 acc = {};
    const u16* Arow = &h[(size_t)(row0 + lm) * UNITS];
    const u16* Brow = &WcT[(size_t)(n0 + lm) * UNITS];
    #pragma unroll 8
    for (int k0 = 0; k0 < UNITS; k0 += 32) {
        short8 a = *(const short8*)&Arow[k0 + lq * 8];
        short8 b = *(const short8*)&Brow[k0 + lq * 8];
        acc = __builtin_amdgcn_mfma_f32_16x16x32_bf16(a, b, acc, 0, 0, 0);
    }
    int col = n0 + lm;
    float bv = bc[col];
    #pragma unroll
    for (int r = 0; r < 4; ++r) {
        int row = row0 + lq * 4 + r;
        out[(size_t)row * 1024 + col] = acc[r] + bv;
    }
}

// ---------------------------------------------------------------- utilities
__global__ void cvt_f32_bf16(const float* __restrict__ in, u16* __restrict__ out, int n) {
    int i = blockIdx.x * 256 + threadIdx.x;
    if (i < n) out[i] = f2bf(in[i]);
}
__global__ void cvt_bf16_f32(const u16* __restrict__ in, float* __restrict__ out, int n) {
    int i = blockIdx.x * 256 + threadIdx.x;
    if (i < n) out[i] = bf2f(in[i]);
}
__global__ void copy_f32(const float* __restrict__ in, float* __restrict__ out, int n) {
    int i = blockIdx.x * 256 + threadIdx.x;
    if (i < n) out[i] = in[i];
}
__global__ void zero_u32(unsigned* __restrict__ p, int n) {
    int i = blockIdx.x * 256 + threadIdx.x;
    if (i < n) p[i] = 0u;
}

// ---------------------------------------------------------------- launch
extern "C" void kernel_launch(void* const* d_in, const int* in_sizes, int n_in,
                              void* d_out, int out_size, void* d_ws, size_t ws_size,
                              hipStream_t stream)
{
    const float* x     = (const float*)d_in[0];   // [128,256,1024]
    const float* h0    = (const float*)d_in[1];   // [128,1024]
    const float* c0    = (const float*)d_in[2];   // [128,1024]
    const float* Wk    = (const float*)d_in[3];   // [1024,4096]
    const float* bk    = (const float*)d_in[4];   // [4096]
    const float* Wr    = (const float*)d_in[5];   // [1024,4096]
    const float* br    = (const float*)d_in[6];   // [4096]
    const float* alpha = (const float*)d_in[7];   // [1,4096]
    const float* beta1 = (const float*)d_in[8];   // [1,4096]
    const float* beta2 = (const float*)d_in[9];   // [1,4096]
    const float* Wc    = (const float*)d_in[10];  // [1024,1024]
    const float* bc    = (const float*)d_in[11];  // [1024]
    float* out = (float*)d_out;                   // out|h|c, each 128*1024 fp32

    char* p = (char*)d_ws;
    u16* h0bf = (u16*)p;  p += (size_t)B_SZ * UNITS * 2;
    u16* hb0  = (u16*)p;  p += (size_t)B_SZ * UNITS * 2;
    u16* hb1  = (u16*)p;  p += (size_t)B_SZ * UNITS * 2;
    float* cbuf = (float*)p; p += (size_t)B_SZ * UNITS * 4;
    unsigned* bar = (unsigned*)p; p += 8 * 64 * 4;    // 8 groups x 256B line
    u16* WkT = (u16*)p;   p += (size_t)FOURU * D_IN * 2;
    u16* WrT = (u16*)p;   p += (size_t)FOURU * UNITS * 2;
    u16* WcT = (u16*)p;   p += (size_t)1024 * 1024 * 2;
    u16* XPc = (u16*)p;   // bf16 permuted [B_SZ*tc][4096]

    size_t fixedB = (size_t)(p - (char*)d_ws);
    int tc = 32, tcShift = 5;
    while (tc > 1 && fixedB + (size_t)B_SZ * tc * FOURU * 2 > ws_size) {
        tc >>= 1; tcShift -= 1;
    }

    // 1) weight transposes + fp32->bf16 convert
    transpose_cvt<<<dim3(FOURU / 32, D_IN / 32), 256, 0, stream>>>(Wk, WkT, D_IN, FOURU);
    transpose_cvt<<<dim3(FOURU / 32, UNITS / 32), 256, 0, stream>>>(Wr, WrT, UNITS, FOURU);
    transpose_cvt<<<dim3(1024 / 32, 1024 / 32), 256, 0, stream>>>(Wc, WcT, 1024, 1024);

    // 2) state init
    cvt_f32_bf16<<<(B_SZ * UNITS) / 256, 256, 0, stream>>>(h0, h0bf, B_SZ * UNITS);
    copy_f32<<<(B_SZ * UNITS) / 256, 256, 0, stream>>>(c0, cbuf, B_SZ * UNITS);
    zero_u32<<<2, 256, 0, stream>>>(bar, 512);

    // 3) recurrence: per chunk, XP GEMM then one persistent chunk kernel.
    //    256 blocks x 512 thr, ~55KB LDS, <=256 VGPR -> 1 block/CU resident.
    for (int t0 = 0; t0 < T_SZ; t0 += tc) {
        gemm_xp_chunk<<<dim3(tc, FOURU / 128), 256, 0, stream>>>(
            x, WkT, bk, XPc, t0, tcShift);
        int nbase = (t0 / tc) * (tc - 1);   // executed barriers before chunk
        milstm_chunk<<<256, 512, 0, stream>>>(
            XPc, WrT, br, alpha, beta1, beta2, h0bf, hb0, hb1, cbuf, bar,
            t0, tc, tcShift, nbase);
    }
    // T=256 even -> final h in hb1

    // 4) out = h @ Wc + bc ; emit h (bf16->f32), c (f32)
    gemm_out<<<128, 256, 0, stream>>>(hb1, WcT, bc, out);
    cvt_bf16_f32<<<(B_SZ * UNITS) / 256, 256, 0, stream>>>(hb1, out + B_SZ * UNITS, B_SZ * UNITS);
    copy_f32<<<(B_SZ * UNITS) / 256, 256, 0, stream>>>(cbuf, out + 2 * B_SZ * UNITS, B_SZ * UNITS);
}

// Round 7
// 2145.509 us; speedup vs baseline: 1.2818x; 1.0478x over previous
//
#include <hip/hip_runtime.h>

// MI-LSTM on MI355X (gfx950). I/O is FP32 (per reference dtypes); compute
// uses bf16 MFMA internally (test tolerance is bf16-grade: 1.156e-2).
// B=128, T=256, D_IN=1024, UNITS=1024, N_CLASS=1024.
//
// R12: attack the XP GEMM exposure (~800us of 2248). R11's gemm_xp was
// VALU-bound (344 TF) on fp32->bf16 staging converts. Now: (1) per-chunk
// cvt kernel pre-converts x to row'-major bf16 xb (8MB); (2) gemm_xp stages
// BOTH operands via __builtin_amdgcn_global_load_lds width=16 (m97 pattern,
// linear LDS, pitch-32 frag reads) -- no VALU in staging at all;
// (3) milstm's 32 serialized barrier arrives become a 4x8+root tree
// (R9-proven counting discipline). Recurrence otherwise identical to R11
// (weights half-in-registers, 32KB swizzled h-stage, sc1 h exchange,
// executed-barrier-counted far-atomic group barrier).

typedef unsigned short u16;
typedef unsigned long long u64t;
typedef __attribute__((ext_vector_type(8))) short short8;   // 8 x bf16 (4 VGPRs)
typedef __attribute__((ext_vector_type(4))) float f32x4;    // MFMA accumulator

#define B_SZ   128
#define T_SZ   256
#define D_IN   1024
#define UNITS  1024
#define FOURU  4096

__device__ __forceinline__ float bf2f(u16 h) {
    return __uint_as_float(((unsigned int)h) << 16);
}
__device__ __forceinline__ u16 f2bf(float f) {
    unsigned int u = __float_as_uint(f);
    u += 0x7fffu + ((u >> 16) & 1u);   // round-to-nearest-even
    return (u16)(u >> 16);
}
__device__ __forceinline__ float sigmoidf_(float x) {
    return 1.0f / (1.0f + __expf(-x));
}

// ---------------------------------------------------------------- transpose+cvt
__global__ __launch_bounds__(256) void transpose_cvt(
    const float* __restrict__ in, u16* __restrict__ out, int K, int N)
{
    __shared__ u16 t[32][33];
    int n0 = blockIdx.x * 32, k0 = blockIdx.y * 32;
    int c = threadIdx.x & 31, r = threadIdx.x >> 5;
    #pragma unroll
    for (int i = 0; i < 4; ++i) {
        int kk = r + i * 8;
        t[kk][c] = f2bf(in[(size_t)(k0 + kk) * N + n0 + c]);
    }
    __syncthreads();
    #pragma unroll
    for (int i = 0; i < 4; ++i) {
        int nn = r + i * 8;
        out[(size_t)(n0 + nn) * K + k0 + c] = t[c][nn];
    }
}

// ---------------------------------------------------------------- x chunk convert
// xb[rowp][k] = bf16(x[b][t0+tt][k]), rowp = b*tc + tt. One block per row'.
__global__ __launch_bounds__(256) void cvt_x_chunk(
    const float* __restrict__ x, u16* __restrict__ xb,
    int t0, int tcShift)
{
    int rowp = blockIdx.x;
    int tcMask = (1 << tcShift) - 1;
    int b = rowp >> tcShift, tt = rowp & tcMask;
    const float* src = &x[(size_t)(b * T_SZ + t0 + tt) * D_IN + threadIdx.x * 4];
    float4 f = *(const float4*)src;
    u64t v = (u64t)f2bf(f.x) | ((u64t)f2bf(f.y) << 16)
           | ((u64t)f2bf(f.z) << 32) | ((u64t)f2bf(f.w) << 48);
    *(u64t*)&xb[(size_t)rowp * D_IN + threadIdx.x * 4] = v;
}

// ---------------------------------------------------------------- XP GEMM (one time-chunk)
// Cc[rowp][ (n&1023)*4 + (n>>10) ] = bf16( xb[rowp][:] @ WkT^T + bk ).
// m97-style staging: global_load_lds width=16 for both operands, linear LDS.
__global__ __launch_bounds__(256) void gemm_xp_chunk(
    const u16* __restrict__ xb, const u16* __restrict__ Bt,
    const float* __restrict__ bias, u16* __restrict__ Cc)
{
    __shared__ __align__(16) u16 As[128 * 32];
    __shared__ __align__(16) u16 Bs[128 * 32];
    int tid = threadIdx.x;
    int wave = tid >> 6, lane = tid & 63;
    int bm = blockIdx.x * 128;     // row' base
    int bn = blockIdx.y * 128;
    int wm = (wave & 1) * 64, wn = (wave >> 1) * 64;
    int lm = lane & 15, lq = lane >> 4;

    // per-lane source row/quarter for the two staging iterations
    int r0 = (tid) >> 2,        q0 = tid & 3;          // i = 0
    int r1 = (tid + 256) >> 2,  q1 = tid & 3;          // i = 1

    f32x4 acc[4][4] = {};

    for (int k0 = 0; k0 < D_IN; k0 += 32) {
        // A tile: 128 rows x 32 k, linear LDS (lane order = r*32 + q*8)
        __builtin_amdgcn_global_load_lds(
            (const __attribute__((address_space(1))) unsigned int*)
                &xb[(size_t)(bm + r0) * D_IN + k0 + q0 * 8],
            (__attribute__((address_space(3))) unsigned int*)&As[wave * 512],
            16, 0, 0);
        __builtin_amdgcn_global_load_lds(
            (const __attribute__((address_space(1))) unsigned int*)
                &xb[(size_t)(bm + r1) * D_IN + k0 + q1 * 8],
            (__attribute__((address_space(3))) unsigned int*)&As[2048 + wave * 512],
            16, 0, 0);
        // B tile
        __builtin_amdgcn_global_load_lds(
            (const __attribute__((address_space(1))) unsigned int*)
                &Bt[(size_t)(bn + r0) * D_IN + k0 + q0 * 8],
            (__attribute__((address_space(3))) unsigned int*)&Bs[wave * 512],
            16, 0, 0);
        __builtin_amdgcn_global_load_lds(
            (const __attribute__((address_space(1))) unsigned int*)
                &Bt[(size_t)(bn + r1) * D_IN + k0 + q1 * 8],
            (__attribute__((address_space(3))) unsigned int*)&Bs[2048 + wave * 512],
            16, 0, 0);
        __syncthreads();
        short8 af[4], bf[4];
        #pragma unroll
        for (int t = 0; t < 4; ++t) {
            af[t] = *(const short8*)&As[(wm + t * 16 + lm) * 32 + lq * 8];
            bf[t] = *(const short8*)&Bs[(wn + t * 16 + lm) * 32 + lq * 8];
        }
        #pragma unroll
        for (int mt = 0; mt < 4; ++mt)
            #pragma unroll
            for (int nt = 0; nt < 4; ++nt)
                acc[mt][nt] = __builtin_amdgcn_mfma_f32_16x16x32_bf16(
                    af[mt], bf[nt], acc[mt][nt], 0, 0, 0);
        __syncthreads();
    }

    #pragma unroll
    for (int mt = 0; mt < 4; ++mt) {
        #pragma unroll
        for (int nt = 0; nt < 4; ++nt) {
            int col = bn + wn + nt * 16 + lm;            // n in [0,4096)
            int colp = ((col & 1023) << 2) | (col >> 10);
            float bv = bias[col];
            #pragma unroll
            for (int r = 0; r < 4; ++r) {
                int rowp = bm + wm + mt * 16 + lq * 4 + r;
                Cc[(size_t)rowp * FOURU + colp] = f2bf(acc[mt][nt][r] + bv);
            }
        }
    }
}

// ---------------------------------------------------------------- persistent LSTM chunk (R12)
// Identical to R11 except the group barrier arrive is a 4x8+root tree.
// 256 blocks x 512 threads. grp = bid>>5 (8 groups x 16 batch rows),
// cb = bid&31 -> 32 u x 4 gates = 128 n-cols. Wave w: kh=w>>2, nq=w&3.
// Wr slice in 128 VGPR/lane (loaded once/chunk); 32KB XOR-swizzled h-stage;
// sc1 h exchange; executed-barrier-counted far-atomic group barrier.
__global__ __launch_bounds__(512) void milstm_chunk(
    const u16* __restrict__ XPc,     // permuted bf16 [128*tc][4096]
    const u16* __restrict__ WrT,     // [4096][1024] bf16
    const float* __restrict__ br,
    const float* __restrict__ alpha,
    const float* __restrict__ beta1,
    const float* __restrict__ beta2,
    const u16* __restrict__ h0bf,    // [128][1024] bf16
    u16* __restrict__ hb0,
    u16* __restrict__ hb1,
    float* __restrict__ cbuf,        // [128][1024] f32
    unsigned* __restrict__ bar,      // 8 groups x 256 u32 (zeroed at t=0)
    int t0, int tc, int tcShift, int nbase)
{
    __shared__ __align__(16) u16 hS[16 * 1024];       // 32KB, XOR-swizzled
    __shared__ __align__(16) float zb[2][128][20];    // 20.5KB, padded
    __shared__ float brS[128], alS[128], b1S[128], b2S[128];

    int tid = threadIdx.x;
    int wave = tid >> 6, lane = tid & 63;
    int lm = lane & 15, lq = lane >> 4;
    int kh = wave >> 2, nq = wave & 3;
    int bid = blockIdx.x;
    int grp = bid >> 5, cb = bid & 31;
    int row0 = grp * 16;
    int ubase = cb * 32;
    unsigned gOff = (unsigned)grp * 256u;
    unsigned sub = (unsigned)(cb >> 3);        // 4 subs x 8 blocks

    // ---- prologue ----
    if (tid < 128) {
        int n = ((tid & 3) << 10) + ubase + (tid >> 2);
        brS[tid] = br[n]; alS[tid] = alpha[n];
        b1S[tid] = beta1[n]; b2S[tid] = beta2[n];
    }
    // Wr slice into registers: 16 k-iters x 2 col-tiles, 128 VGPR/lane
    short8 Breg[32];
    #pragma unroll
    for (int j = 0; j < 16; ++j) {
        #pragma unroll
        for (int nt = 0; nt < 2; ++nt) {
            int c = nq * 32 + nt * 16 + lm;
            int n = ((c & 3) << 10) + ubase + (c >> 2);
            int k = kh * 512 + j * 32 + lq * 8;
            Breg[j * 2 + nt] = *(const short8*)&WrT[(size_t)n * 1024 + k];
        }
    }
    // epilogue cell: row = tid&15, u_loc = tid>>4
    int erow = tid & 15, eul = tid >> 4;
    size_t hix = (size_t)(row0 + erow) * UNITS + ubase + eul;
    float cv = cbuf[hix];
    u64t xq = *(const u64t*)&XPc[((size_t)((row0 + erow) << tcShift) + 0) * FOURU
                                 + (size_t)(ubase + eul) * 4];
    // h-stage thread mapping: row sr = tid>>5, 64B chunk sc = tid&31
    int sr = tid >> 5, sc = tid & 31;
    unsigned swzS = (unsigned)((sr & 7) << 4);

    for (int s = 0; s < tc; ++s) {
        int t = t0 + s;
        const u16* hsrc = (t == 0) ? h0bf : ((t & 1) ? hb0 : hb1);
        u16* hdst = (t & 1) ? hb1 : hb0;

        // ---- stage group-h into LDS: 8 sc1 u64 loads + 4 swizzled b128 writes
        {
            const u64t* hp8 = (const u64t*)&hsrc[(size_t)(row0 + sr) * UNITS] + sc * 8;
            u64t aq[8];
            #pragma unroll
            for (int i = 0; i < 8; ++i)
                aq[i] = __hip_atomic_load(hp8 + i, __ATOMIC_RELAXED, __HIP_MEMORY_SCOPE_AGENT);
            char* dst = (char*)hS + sr * 2048;
            int base = sc * 64;
            #pragma unroll
            for (int q = 0; q < 4; ++q) {
                uint4 v;
                v.x = (unsigned)aq[2 * q];     v.y = (unsigned)(aq[2 * q] >> 32);
                v.z = (unsigned)aq[2 * q + 1]; v.w = (unsigned)(aq[2 * q + 1] >> 32);
                *(uint4*)(dst + (((unsigned)(base + q * 16)) ^ swzS)) = v;
            }
        }
        __syncthreads();   // sync1: h-stage ready

        // ---- hp partial GEMM: 16 k-iters, A from swizzled hS, B from regs
        f32x4 acc0 = {}, acc1 = {};
        {
            unsigned swzA = (unsigned)((lm & 7) << 4);
            const char* hb = (const char*)hS + lm * 2048;
            #pragma unroll
            for (int j = 0; j < 16; ++j) {
                unsigned koff = (unsigned)(kh * 1024 + j * 64 + lq * 16);
                short8 a = *(const short8*)(hb + (koff ^ swzA));
                acc0 = __builtin_amdgcn_mfma_f32_16x16x32_bf16(a, Breg[j * 2],     acc0, 0, 0, 0);
                acc1 = __builtin_amdgcn_mfma_f32_16x16x32_bf16(a, Breg[j * 2 + 1], acc1, 0, 0, 0);
            }
        }
        *(f32x4*)&zb[kh][nq * 32 + lm][lq * 4]      = acc0;
        *(f32x4*)&zb[kh][nq * 32 + 16 + lm][lq * 4] = acc1;
        __syncthreads();   // sync2: both zbuf layers complete

        // ---- fused MI epilogue: cell (row0+erow, ubase+eul)
        {
            float zz[4];
            #pragma unroll
            for (int g = 0; g < 4; ++g) {
                int c = eul * 4 + g;
                float hp = zb[0][c][erow] + zb[1][c][erow] + brS[c];
                float xp = bf2f((u16)(xq >> (16 * g)));
                zz[g] = alS[c] * xp * hp + b1S[c] * xp + b2S[c] * hp;
            }
            float cn = tanhf(zz[2]) * sigmoidf_(zz[0]) + cv * sigmoidf_(zz[1]);
            cv = cn;
            u16 hv = f2bf(tanhf(cn) * sigmoidf_(zz[3]));
            __hip_atomic_store(&hdst[hix], hv, __ATOMIC_RELAXED, __HIP_MEMORY_SCOPE_AGENT);
        }
        if (s + 1 < tc) {
            // next-step XP prefetch (plain cached load; XPc constant in chunk)
            xq = *(const u64t*)&XPc[((size_t)((row0 + erow) << tcShift) + s + 1) * FOURU
                                     + (size_t)(ubase + eul) * 4];
            __syncthreads();   // sync3: h sc1 stores vmcnt-drained block-wide
            if (tid == 0) {
                unsigned barId = (unsigned)(nbase + s + 1);
                unsigned old = __hip_atomic_fetch_add(&bar[gOff + sub * 32u], 1u,
                                   __ATOMIC_RELAXED, __HIP_MEMORY_SCOPE_AGENT);
                if (old == 8u * barId - 1u)
                    __hip_atomic_fetch_add(&bar[gOff + 128u], 1u,
                        __ATOMIC_RELAXED, __HIP_MEMORY_SCOPE_AGENT);
                while (__hip_atomic_load(&bar[gOff + 128u],
                           __ATOMIC_RELAXED, __HIP_MEMORY_SCOPE_AGENT)
                       < 4u * barId)
                    __builtin_amdgcn_s_sleep(1);
            }
            __syncthreads();   // sync4: release; safe to overwrite hS/zb
        }
    }

    // c-state writeback once per chunk (plain; kernel-end release flushes)
    cbuf[hix] = cv;
}

// ---------------------------------------------------------------- final GEMM
__global__ __launch_bounds__(256) void gemm_out(
    const u16* __restrict__ h, const u16* __restrict__ WcT,
    const float* __restrict__ bc, float* __restrict__ out)
{
    int tid = threadIdx.x;
    int wave = tid >> 6, lane = tid & 63;
    int bx = blockIdx.x;
    int row0 = (bx & 7) * 16;
    int n0 = (bx >> 3) * 64 + wave * 16;
    int lm = lane & 15, lq = lane >> 4;

    f32x4 acc = {};
    const u16* Arow = &h[(size_t)(row0 + lm) * UNITS];
    const u16* Brow = &WcT[(size_t)(n0 + lm) * UNITS];
    #pragma unroll 8
    for (int k0 = 0; k0 < UNITS; k0 += 32) {
        short8 a = *(const short8*)&Arow[k0 + lq * 8];
        short8 b = *(const short8*)&Brow[k0 + lq * 8];
        acc = __builtin_amdgcn_mfma_f32_16x16x32_bf16(a, b, acc, 0, 0, 0);
    }
    int col = n0 + lm;
    float bv = bc[col];
    #pragma unroll
    for (int r = 0; r < 4; ++r) {
        int row = row0 + lq * 4 + r;
        out[(size_t)row * 1024 + col] = acc[r] + bv;
    }
}

// ---------------------------------------------------------------- utilities
__global__ void cvt_f32_bf16(const float* __restrict__ in, u16* __restrict__ out, int n) {
    int i = blockIdx.x * 256 + threadIdx.x;
    if (i < n) out[i] = f2bf(in[i]);
}
__global__ void cvt_bf16_f32(const u16* __restrict__ in, float* __restrict__ out, int n) {
    int i = blockIdx.x * 256 + threadIdx.x;
    if (i < n) out[i] = bf2f(in[i]);
}
__global__ void copy_f32(const float* __restrict__ in, float* __restrict__ out, int n) {
    int i = blockIdx.x * 256 + threadIdx.x;
    if (i < n) out[i] = in[i];
}
__global__ void zero_u32(unsigned* __restrict__ p, int n) {
    int i = blockIdx.x * 256 + threadIdx.x;
    if (i < n) p[i] = 0u;
}

// ---------------------------------------------------------------- launch
extern "C" void kernel_launch(void* const* d_in, const int* in_sizes, int n_in,
                              void* d_out, int out_size, void* d_ws, size_t ws_size,
                              hipStream_t stream)
{
    const float* x     = (const float*)d_in[0];   // [128,256,1024]
    const float* h0    = (const float*)d_in[1];   // [128,1024]
    const float* c0    = (const float*)d_in[2];   // [128,1024]
    const float* Wk    = (const float*)d_in[3];   // [1024,4096]
    const float* bk    = (const float*)d_in[4];   // [4096]
    const float* Wr    = (const float*)d_in[5];   // [1024,4096]
    const float* br    = (const float*)d_in[6];   // [4096]
    const float* alpha = (const float*)d_in[7];   // [1,4096]
    const float* beta1 = (const float*)d_in[8];   // [1,4096]
    const float* beta2 = (const float*)d_in[9];   // [1,4096]
    const float* Wc    = (const float*)d_in[10];  // [1024,1024]
    const float* bc    = (const float*)d_in[11];  // [1024]
    float* out = (float*)d_out;                   // out|h|c, each 128*1024 fp32

    char* p = (char*)d_ws;
    u16* h0bf = (u16*)p;  p += (size_t)B_SZ * UNITS * 2;
    u16* hb0  = (u16*)p;  p += (size_t)B_SZ * UNITS * 2;
    u16* hb1  = (u16*)p;  p += (size_t)B_SZ * UNITS * 2;
    float* cbuf = (float*)p; p += (size_t)B_SZ * UNITS * 4;
    unsigned* bar = (unsigned*)p; p += 8 * 256 * 4;   // 8 groups x 1KB
    u16* WkT = (u16*)p;   p += (size_t)FOURU * D_IN * 2;
    u16* WrT = (u16*)p;   p += (size_t)FOURU * UNITS * 2;
    u16* WcT = (u16*)p;   p += (size_t)1024 * 1024 * 2;

    size_t fixedB = (size_t)(p - (char*)d_ws);
    // variable part: xb (tc*256KB) + XPc (tc*1MB)
    int tc = 32, tcShift = 5;
    while (tc > 1 && fixedB + (size_t)B_SZ * tc * (D_IN + FOURU * 2) > ws_size) {
        tc >>= 1; tcShift -= 1;
    }
    u16* xb  = (u16*)p;   p += (size_t)B_SZ * tc * D_IN * 2;
    u16* XPc = (u16*)p;   // bf16 permuted [B_SZ*tc][4096]

    // 1) weight transposes + fp32->bf16 convert
    transpose_cvt<<<dim3(FOURU / 32, D_IN / 32), 256, 0, stream>>>(Wk, WkT, D_IN, FOURU);
    transpose_cvt<<<dim3(FOURU / 32, UNITS / 32), 256, 0, stream>>>(Wr, WrT, UNITS, FOURU);
    transpose_cvt<<<dim3(1024 / 32, 1024 / 32), 256, 0, stream>>>(Wc, WcT, 1024, 1024);

    // 2) state init
    cvt_f32_bf16<<<(B_SZ * UNITS) / 256, 256, 0, stream>>>(h0, h0bf, B_SZ * UNITS);
    copy_f32<<<(B_SZ * UNITS) / 256, 256, 0, stream>>>(c0, cbuf, B_SZ * UNITS);
    zero_u32<<<8, 256, 0, stream>>>(bar, 2048);

    // 3) recurrence: per chunk, x-convert + XP GEMM, then persistent kernel.
    for (int t0 = 0; t0 < T_SZ; t0 += tc) {
        cvt_x_chunk<<<B_SZ * tc, 256, 0, stream>>>(x, xb, t0, tcShift);
        gemm_xp_chunk<<<dim3(tc, FOURU / 128), 256, 0, stream>>>(
            xb, WkT, bk, XPc);
        int nbase = (t0 / tc) * (tc - 1);   // executed barriers before chunk
        milstm_chunk<<<256, 512, 0, stream>>>(
            XPc, WrT, br, alpha, beta1, beta2, h0bf, hb0, hb1, cbuf, bar,
            t0, tc, tcShift, nbase);
    }
    // T=256 even -> final h in hb1

    // 4) out = h @ Wc + bc ; emit h (bf16->f32), c (f32)
    gemm_out<<<128, 256, 0, stream>>>(hb1, WcT, bc, out);
    cvt_bf16_f32<<<(B_SZ * UNITS) / 256, 256, 0, stream>>>(hb1, out + B_SZ * UNITS, B_SZ * UNITS);
    copy_f32<<<(B_SZ * UNITS) / 256, 256, 0, stream>>>(cbuf, out + 2 * B_SZ * UNITS, B_SZ * UNITS);
}